// Round 5
// baseline (235.294 us; speedup 1.0000x reference)
//
#include <hip/hip_runtime.h>
#include <math.h>

#ifndef M_PI
#define M_PI 3.14159265358979323846
#endif

// Static problem config (mirrors reference)
#define SS   129                 // density cube side
#define LL   224                 // padded/rotation cube side = ceil(129*sqrt(3))
#define LL2  (LL*LL)
#define LL3  (LL*LL*LL)
#define SS2  (SS*SS)
#define SS3  (SS*SS*SS)
#define CABS 0.2f
#define PAD  48                  // LL/2 - SS/2 = 112 - 64

// Slab bounds in forward-rotated (padded-d) coords. Back-rotation taps reach
// [48-sqrt(3), 176+sqrt(3)] = [46.27,177.73]; margin to 45.5/178.5.
#define BLO 45.5f
#define BHI 178.5f

#define NT1  28                  // K1 tiles per axis (224/8)
#define TPL1 21952               // 28^3
#define NT3  17                  // back tiles per axis (ceil(129/8))
#define TPL3 4913                // 17^3
#define SBL  196                 // LL2/256 scan blocks per light
#define NSEG 4                   // view-ray scan segments
#define SEGZ 33                  // ceil(129/4)

// staging box for an 8^3 output tile (covers worst-case rotated AABB + interp)
#define GLX 16
#define GLY 13
#define GLZ 15
#define GLN (GLX*GLY*GLZ)        // 3120 floats = 12.5 KB

struct Mat3 { float m[9]; };
struct F3   { float x, y, z; };

// linspace(-1,1,224)[i]
__device__ __forceinline__ float nrm(int i) {
    return fmaf((float)i, 2.0f / 223.0f, -1.0f);
}

// q-coords of a tile center. SINGLE shared expression for K1's write-accept
// and K2's read-accept (per-tile uniform -> deterministic, identical).
__device__ __forceinline__ F3 tile_center(const Mat3& M, int ox, int oy, int oz) {
    float cbx = fmaf((float)ox + 3.5f, 2.0f / 223.0f, -1.0f);
    float cby = fmaf((float)oy + 3.5f, 2.0f / 223.0f, -1.0f);
    float cbz = fmaf((float)oz + 3.5f, 2.0f / 223.0f, -1.0f);
    F3 qc;
    qc.x = fmaf(fmaf(M.m[0], cbx, fmaf(M.m[1], cby, M.m[2] * cbz)), 111.5f, 111.5f);
    qc.y = fmaf(fmaf(M.m[3], cbx, fmaf(M.m[4], cby, M.m[5] * cbz)), 111.5f, 111.5f);
    qc.z = fmaf(fmaf(M.m[6], cbx, fmaf(M.m[7], cby, M.m[8] * cbz)), 111.5f, 111.5f);
    return qc;
}

__device__ __forceinline__ bool tile_accept(F3 qc, F3 H) {
    return !(qc.x + H.x < BLO || qc.x - H.x > BHI ||
             qc.y + H.y < BLO || qc.y - H.y > BHI ||
             qc.z + H.z < BLO || qc.z - H.z > BHI);
}

// full-precision map (fallback path only)
__device__ __forceinline__ void qmap(const Mat3& M, int x, int y, int z,
                                     float& qx, float& qy, float& qz) {
    float bx = nrm(x), by = nrm(y), bz = nrm(z);
    qx = fmaf(fmaf(M.m[0], bx, fmaf(M.m[1], by, M.m[2] * bz)), 111.5f, 111.5f);
    qy = fmaf(fmaf(M.m[3], bx, fmaf(M.m[4], by, M.m[5] * bz)), 111.5f, 111.5f);
    qz = fmaf(fmaf(M.m[6], bx, fmaf(M.m[7], by, M.m[8] * bz)), 111.5f, 111.5f);
}

// padded-volume fetch: zero outside the centered SS^3 region
__device__ __forceinline__ float fetch_d(const float* __restrict__ d, int z, int y, int x) {
    unsigned zz = (unsigned)(z - PAD), yy = (unsigned)(y - PAD), xx = (unsigned)(x - PAD);
    return (zz < (unsigned)SS && yy < (unsigned)SS && xx < (unsigned)SS)
        ? d[((int)zz * SS + (int)yy) * SS + (int)xx] : 0.0f;
}

// transmittance-volume fetch: zero outside [0,LL)^3
__device__ __forceinline__ float fetch_T(const float* __restrict__ T, int z, int y, int x) {
    unsigned zz = (unsigned)z, yy = (unsigned)y, xx = (unsigned)x;
    return (zz < (unsigned)LL && yy < (unsigned)LL && xx < (unsigned)LL)
        ? T[((int)zz * LL + (int)yy) * LL + (int)xx] : 0.0f;
}

__device__ __forceinline__ float tri_T(const float* __restrict__ T, float qz, float qy, float qx) {
    int x0 = (int)floorf(qx), y0 = (int)floorf(qy), z0 = (int)floorf(qz);
    float wx = qx - (float)x0, wy = qy - (float)y0, wz = qz - (float)z0;
    float c000 = fetch_T(T, z0,     y0,     x0    );
    float c001 = fetch_T(T, z0,     y0,     x0 + 1);
    float c010 = fetch_T(T, z0,     y0 + 1, x0    );
    float c011 = fetch_T(T, z0,     y0 + 1, x0 + 1);
    float c100 = fetch_T(T, z0 + 1, y0,     x0    );
    float c101 = fetch_T(T, z0 + 1, y0,     x0 + 1);
    float c110 = fetch_T(T, z0 + 1, y0 + 1, x0    );
    float c111 = fetch_T(T, z0 + 1, y0 + 1, x0 + 1);
    float a00 = c000 + wx * (c001 - c000);
    float a01 = c010 + wx * (c011 - c010);
    float a10 = c100 + wx * (c101 - c100);
    float a11 = c110 + wx * (c111 - c110);
    float b0  = a00 + wy * (a01 - a00);
    float b1  = a10 + wy * (a11 - a10);
    return b0 + wz * (b1 - b0);
}

// shared trilinear-from-LDS
__device__ __forceinline__ float tri_lds(const float S[GLZ][GLY][GLX],
                                         float qx, float qy, float qz,
                                         int lox, int loy, int loz) {
    int gx0 = (int)floorf(qx), gy0 = (int)floorf(qy), gz0 = (int)floorf(qz);
    float wx = qx - (float)gx0, wy = qy - (float)gy0, wz = qz - (float)gz0;
    int x0 = gx0 - lox, y0 = gy0 - loy, z0 = gz0 - loz;
    float c000 = S[z0    ][y0    ][x0    ];
    float c001 = S[z0    ][y0    ][x0 + 1];
    float c010 = S[z0    ][y0 + 1][x0    ];
    float c011 = S[z0    ][y0 + 1][x0 + 1];
    float c100 = S[z0 + 1][y0    ][x0    ];
    float c101 = S[z0 + 1][y0    ][x0 + 1];
    float c110 = S[z0 + 1][y0 + 1][x0    ];
    float c111 = S[z0 + 1][y0 + 1][x0 + 1];
    float a00 = c000 + wx * (c001 - c000);
    float a01 = c010 + wx * (c011 - c010);
    float a10 = c100 + wx * (c101 - c100);
    float a11 = c110 + wx * (c111 - c110);
    float b0  = a00 + wy * (a01 - a00);
    float b1  = a10 + wy * (a11 - a10);
    return b0 + wz * (b1 - b0);
}

// K1: rotated density; accepted tiles write ALL their voxels (no per-voxel
// predicate; out-of-support samples are exactly 0).
__global__ __launch_bounds__(512) void k_rot_density(const float* __restrict__ d,
        float* __restrict__ T0, float* __restrict__ T1,
        Mat3 M0, Mat3 M1, F3 H0, F3 H1, int lbase) {
    int b = blockIdx.x;
    int lofs = b / TPL1; b -= lofs * TPL1;
    int light = lbase + lofs;
    const Mat3 M = light ? M1 : M0;
    const F3  H  = light ? H1 : H0;
    float* __restrict__ T = light ? T1 : T0;

    int ttx = b % NT1; int rr = b / NT1; int tty = rr % NT1; int ttz = rr / NT1;
    int ox = ttx * 8, oy = tty * 8, oz = ttz * 8;
    F3 qc = tile_center(M, ox, oy, oz);
    if (!tile_accept(qc, H)) return;

    int lox = (int)floorf(qc.x - H.x);
    int loy = (int)floorf(qc.y - H.y);
    int loz = (int)floorf(qc.z - H.z);

    __shared__ float S[GLZ][GLY][GLX];
    for (int idx = threadIdx.x; idx < GLN; idx += 512) {
        int ix = idx % GLX; int t2 = idx / GLX; int iy = t2 % GLY; int iz = t2 / GLY;
        S[iz][iy][ix] = fetch_d(d, loz + iz, loy + iy, lox + ix);
    }
    __syncthreads();

    int lx = threadIdx.x & 7, ly = (threadIdx.x >> 3) & 7, lz = threadIdx.x >> 6;
    float fx = (float)lx - 3.5f, fy = (float)ly - 3.5f, fz = (float)lz - 3.5f;
    // grid step in q-units is exactly 1 voxel -> q = qc + M*(fx,fy,fz)
    float qx = qc.x + fmaf(M.m[0], fx, fmaf(M.m[1], fy, M.m[2] * fz));
    float qy = qc.y + fmaf(M.m[3], fx, fmaf(M.m[4], fy, M.m[5] * fz));
    float qz = qc.z + fmaf(M.m[6], fx, fmaf(M.m[7], fy, M.m[8] * fz));

    float v = tri_lds(S, qx, qy, qz, lox, loy, loz);
    T[((oz + lz) * LL + (oy + ly)) * LL + (ox + lx)] = v;
}

// K2: reverse cumsum + exp over the contiguous run of accepted tiles per column
__global__ __launch_bounds__(256) void k_scan_exp(float* __restrict__ T0,
        float* __restrict__ T1, Mat3 M0, Mat3 M1, F3 H0, F3 H1, int lbase) {
    int b = blockIdx.x;
    int lofs = b / SBL;
    int col = (b - lofs * SBL) * 256 + threadIdx.x;   // < LL2 exactly
    int light = lbase + lofs;
    const Mat3 M = light ? M1 : M0;
    const F3  H  = light ? H1 : H0;
    float* __restrict__ Tc = (light ? T1 : T0) + col;
    int x = col % LL, y = col / LL;
    int tox = (x >> 3) << 3, toy = (y >> 3) << 3;

    // EXACT same acceptance computation as K1 (same ints in, same fp expr)
    int t0 = -1, t1 = -1;
    for (int t = 0; t < NT1; ++t) {
        F3 qc = tile_center(M, tox, toy, t << 3);
        if (tile_accept(qc, H)) { if (t0 < 0) t0 = t; t1 = t; }
    }
    if (t0 < 0) return;
    int zbot = t0 << 3, ztop = (t1 << 3) + 7;

    // batched: 8 independent loads, then exp; stores guarded to [zbot,ztop]
    float run = 0.0f;
    int z = ztop;
    int nch = (ztop - zbot + 8) >> 3;
    for (int c = 0; c < nch; ++c) {
        float v[8];
        #pragma unroll
        for (int j = 0; j < 8; ++j) {
            int zz = max(z - j, zbot);
            v[j] = Tc[zz * LL2];
        }
        #pragma unroll
        for (int j = 0; j < 8; ++j) {
            run += v[j];                       // pad adds occur after all real z
            float e = __expf(-CABS * run);
            if (z - j >= zbot) Tc[(z - j) * LL2] = e;
        }
        z -= 8;
    }
}

// W precompute: W[z,col] = d * exp(-c * suffix-sum(d))  (view-ray weights)
__global__ __launch_bounds__(256) void k_w_seg(const float* __restrict__ d,
                                               float* __restrict__ Dseg) {
    int t = blockIdx.x * 256 + threadIdx.x;
    if (t >= NSEG * SS2) return;
    int seg = t / SS2, col = t - seg * SS2;
    int zs = seg * SEGZ, ze = min(SS, zs + SEGZ);
    float run = 0.0f;
    for (int z = zs; z < ze; ++z) run += d[z * SS2 + col];
    Dseg[t] = run;
}

__global__ __launch_bounds__(256) void k_w_write(const float* __restrict__ d,
                                                 const float* __restrict__ Dseg,
                                                 float* __restrict__ W) {
    int t = blockIdx.x * 256 + threadIdx.x;
    if (t >= NSEG * SS2) return;
    int seg = t / SS2, col = t - seg * SS2;
    int zs = seg * SEGZ, ze = min(SS, zs + SEGZ);
    float run = 0.0f;
    for (int s2 = seg + 1; s2 < NSEG; ++s2) run += Dseg[s2 * SS2 + col];
    for (int z = ze - 1; z >= zs; --z) {
        float dv = d[z * SS2 + col];
        run += dv;
        W[z * SS2 + col] = dv * __expf(-CABS * run);
    }
}

// K3': back-rotate + multiply by W + reduce 8 z-lanes per column + atomic acc
__global__ __launch_bounds__(512) void k_back_acc(const float* __restrict__ T,
        const float* __restrict__ W, float* __restrict__ A, Mat3 M, F3 H) {
    int b = blockIdx.x;
    int ttx = b % NT3; int rr = b / NT3; int tty = rr % NT3; int ttz = rr / NT3;
    int ox = ttx * 8, oy = tty * 8, oz = ttz * 8;
    F3 qc = tile_center(M, ox + PAD, oy + PAD, oz + PAD);
    int lox = (int)floorf(qc.x - H.x);
    int loy = (int)floorf(qc.y - H.y);
    int loz = (int)floorf(qc.z - H.z);

    __shared__ float S[GLZ][GLY][GLX];
    __shared__ float red[64];
    for (int idx = threadIdx.x; idx < GLN; idx += 512) {
        int ix = idx % GLX; int t2 = idx / GLX; int iy = t2 % GLY; int iz = t2 / GLY;
        S[iz][iy][ix] = fetch_T(T, loz + iz, loy + iy, lox + ix);
    }
    if (threadIdx.x < 64) red[threadIdx.x] = 0.0f;
    __syncthreads();

    int lx = threadIdx.x & 7, ly = (threadIdx.x >> 3) & 7, lz = threadIdx.x >> 6;
    int x = ox + lx, y = oy + ly, z = oz + lz;
    if (x < SS && y < SS && z < SS) {
        float fx = (float)lx - 3.5f, fy = (float)ly - 3.5f, fz = (float)lz - 3.5f;
        float qx = qc.x + fmaf(M.m[0], fx, fmaf(M.m[1], fy, M.m[2] * fz));
        float qy = qc.y + fmaf(M.m[3], fx, fmaf(M.m[4], fy, M.m[5] * fz));
        float qz = qc.z + fmaf(M.m[6], fx, fmaf(M.m[7], fy, M.m[8] * fz));
        float u = tri_lds(S, qx, qy, qz, lox, loy, loz);
        float v = u * W[(z * SS + y) * SS + x];
        atomicAdd(&red[(ly << 3) | lx], v);
    }
    __syncthreads();
    if (threadIdx.x < 64) {
        int xx = ox + (threadIdx.x & 7), yy = oy + (threadIdx.x >> 3);
        if (xx < SS && yy < SS) atomicAdd(&A[yy * SS + xx], red[threadIdx.x]);
    }
}

// combine per-light accumulators -> RGB output
__global__ __launch_bounds__(256) void k_combine(const float* __restrict__ A0,
        const float* __restrict__ A1, float* __restrict__ out, F3 c0, F3 c1) {
    int i = blockIdx.x * 256 + threadIdx.x;
    if (i >= 3 * SS2) return;
    int ch = i / SS2, col = i - ch * SS2;
    float r0 = (ch == 0) ? c0.x : ((ch == 1) ? c0.y : c0.z);
    float r1 = (ch == 0) ? c1.x : ((ch == 1) ? c1.y : c1.z);
    float o = CABS * (A0[col] * r0 + A1[col] * r1);
    out[i] = fminf(fmaxf(o, 0.0f), 1.0f);
}

// ---- smallest-workspace fallback ----
__global__ __launch_bounds__(64) void k_fused_back(const float* __restrict__ T,
        const float* __restrict__ d, float* __restrict__ LA, Mat3 RT,
        float cr, float cg, float cb, int first) {
    int col = blockIdx.x * 64 + threadIdx.x;
    if (col >= SS2) return;
    int y = col / SS, x = col % SS;
    float run = 0.0f, acc = 0.0f;
    for (int z = SS - 1; z >= 0; --z) {
        float qx, qy, qz; qmap(RT, x + PAD, y + PAD, z + PAD, qx, qy, qz);
        float u = tri_T(T, qz, qy, qx);
        float dv = d[z * SS2 + col];
        run += dv;
        acc = fmaf(dv * __expf(-CABS * run), u, acc);
    }
    if (first) {
        LA[0 * SS2 + col] = acc * cr;
        LA[1 * SS2 + col] = acc * cg;
        LA[2 * SS2 + col] = acc * cb;
    } else {
        LA[0 * SS2 + col] += acc * cr;
        LA[1 * SS2 + col] += acc * cg;
        LA[2 * SS2 + col] += acc * cb;
    }
}

__global__ __launch_bounds__(256) void k_clip(const float* __restrict__ LA,
                                              float* __restrict__ out) {
    int i = blockIdx.x * 256 + threadIdx.x;
    if (i < 3 * SS2) out[i] = fminf(fmaxf(CABS * LA[i], 0.0f), 1.0f);
}

// host: build R (ypr) and its transpose (== rot_matrix(-y,-p,'rpy')) as in reference
static void light_mats(const double ld_in[3], Mat3& R, Mat3& RT) {
    double n = sqrt(ld_in[0]*ld_in[0] + ld_in[1]*ld_in[1] + ld_in[2]*ld_in[2]);
    double l0 = ld_in[0]/n, l1 = ld_in[1]/n, l2 = ld_in[2]/n;
    double yv = -asin(l0);
    if (l2 < 0) yv = -M_PI - yv;
    double yd = yv * 180.0 / M_PI, pd = asin(l1) * 180.0 / M_PI;
    double yr = yd * M_PI / 180.0, pr = pd * M_PI / 180.0;
    float cy = (float)cos(yr), sy = (float)sin(yr), cp = (float)cos(pr), sp = (float)sin(pr);
    float m[9] = { cy,  sy*sp,  sy*cp,
                   0.f, cp,    -sp,
                  -sy,  cy*sp,  cy*cp };
    for (int i = 0; i < 9; ++i) R.m[i] = m[i];
    RT.m[0] = m[0]; RT.m[1] = m[3]; RT.m[2] = m[6];
    RT.m[3] = m[1]; RT.m[4] = m[4]; RT.m[5] = m[7];
    RT.m[6] = m[2]; RT.m[7] = m[5]; RT.m[8] = m[8];
}

// half-span of an 8^3 tile's source AABB (per source axis k: 3.5 * |row_k|_1)
static F3 half_span(const Mat3& M) {
    F3 h;
    h.x = 3.5f * (fabsf(M.m[0]) + fabsf(M.m[1]) + fabsf(M.m[2])) + 0.05f;
    h.y = 3.5f * (fabsf(M.m[3]) + fabsf(M.m[4]) + fabsf(M.m[5])) + 0.05f;
    h.z = 3.5f * (fabsf(M.m[6]) + fabsf(M.m[7]) + fabsf(M.m[8])) + 0.05f;
    return h;
}

extern "C" void kernel_launch(void* const* d_in, const int* in_sizes, int n_in,
                              void* d_out, int out_size, void* d_ws, size_t ws_size,
                              hipStream_t stream) {
    const float* d = (const float*)d_in[0];
    float* out = (float*)d_out;

    const double dirs[2][3] = { {2.0, 1.0, 1.0}, {-1.0, 0.5, 0.0} };
    F3 c0 = { 1.0f, 69.0f / 255.0f, 25.0f / 255.0f };
    F3 c1 = { 227.0f / 255.0f, 1.0f, 66.0f / 255.0f };
    Mat3 R[2], RT[2];
    light_mats(dirs[0], R[0], RT[0]);
    light_mats(dirs[1], R[1], RT[1]);
    F3 HF[2] = { half_span(R[0]),  half_span(R[1])  };
    F3 HB[2] = { half_span(RT[0]), half_span(RT[1]) };

    const size_t need_A = (size_t)(2 * LL3 + SS3 + 6 * SS2) * sizeof(float);  // ~99 MB
    const size_t need_B = (size_t)(LL3 + SS3 + 6 * SS2) * sizeof(float);      // ~54 MB

    if (ws_size >= need_A) {
        float* T0   = (float*)d_ws;
        float* T1   = T0 + LL3;
        float* W    = T1 + LL3;
        float* Dseg = W + SS3;
        float* A0   = Dseg + NSEG * SS2;
        float* A1   = A0 + SS2;
        hipMemsetAsync(A0, 0, 2 * SS2 * sizeof(float), stream);
        k_w_seg  <<<(NSEG * SS2 + 255) / 256, 256, 0, stream>>>(d, Dseg);
        k_w_write<<<(NSEG * SS2 + 255) / 256, 256, 0, stream>>>(d, Dseg, W);
        k_rot_density<<<2 * TPL1, 512, 0, stream>>>(d, T0, T1, R[0], R[1], HF[0], HF[1], 0);
        k_scan_exp   <<<2 * SBL, 256, 0, stream>>>(T0, T1, R[0], R[1], HF[0], HF[1], 0);
        k_back_acc   <<<TPL3, 512, 0, stream>>>(T0, W, A0, RT[0], HB[0]);
        k_back_acc   <<<TPL3, 512, 0, stream>>>(T1, W, A1, RT[1], HB[1]);
        k_combine    <<<(3 * SS2 + 255) / 256, 256, 0, stream>>>(A0, A1, out, c0, c1);
    } else if (ws_size >= need_B) {
        float* T    = (float*)d_ws;
        float* W    = T + LL3;
        float* Dseg = W + SS3;
        float* A0   = Dseg + NSEG * SS2;
        float* A1   = A0 + SS2;
        hipMemsetAsync(A0, 0, 2 * SS2 * sizeof(float), stream);
        k_w_seg  <<<(NSEG * SS2 + 255) / 256, 256, 0, stream>>>(d, Dseg);
        k_w_write<<<(NSEG * SS2 + 255) / 256, 256, 0, stream>>>(d, Dseg, W);
        for (int l = 0; l < 2; ++l) {
            k_rot_density<<<TPL1, 512, 0, stream>>>(d, T, T, R[0], R[1], HF[0], HF[1], l);
            k_scan_exp   <<<SBL, 256, 0, stream>>>(T, T, R[0], R[1], HF[0], HF[1], l);
            k_back_acc   <<<TPL3, 512, 0, stream>>>(T, W, l ? A1 : A0, RT[l], HB[l]);
        }
        k_combine<<<(3 * SS2 + 255) / 256, 256, 0, stream>>>(A0, A1, out, c0, c1);
    } else {
        float* T  = (float*)d_ws;
        float* LA = T + LL3;
        for (int l = 0; l < 2; ++l) {
            k_rot_density<<<TPL1, 512, 0, stream>>>(d, T, T, R[0], R[1], HF[0], HF[1], l);
            k_scan_exp   <<<SBL, 256, 0, stream>>>(T, T, R[0], R[1], HF[0], HF[1], l);
            k_fused_back <<<(SS2 + 63) / 64, 64, 0, stream>>>(T, d, LA, RT[l],
                l ? c1.x : c0.x, l ? c1.y : c0.y, l ? c1.z : c0.z, l == 0);
        }
        k_clip<<<(3 * SS2 + 255) / 256, 256, 0, stream>>>(LA, out);
    }
}

// Round 6
// 202.767 us; speedup vs baseline: 1.1604x; 1.1604x over previous
//
#include <hip/hip_runtime.h>
#include <math.h>

#ifndef M_PI
#define M_PI 3.14159265358979323846
#endif

#define SS   129
#define LL   224
#define LL2  (LL*LL)
#define LL3  (LL*LL*LL)
#define SS2  (SS*SS)
#define SS3  (SS*SS*SS)
#define CABS 0.2f
#define PAD  48

#define BLO 45.5f
#define BHI 178.5f

#define NT1  28
#define TPL1 21952
#define NT3  17
#define TPL3 4913
#define NTZ  28
#define NSEG 4
#define SEGZ 33

#define GD   16
#define GD2  256
#define GD3  4096

struct Mat3 { float m[9]; };
struct F3   { float x, y, z; };

// q-coords of a tile center: SINGLE shared expression for every kernel that
// decides tile acceptance (bitwise-identical across kernels).
__device__ __forceinline__ F3 tile_center(const Mat3& M, int ox, int oy, int oz) {
    float cbx = fmaf((float)ox + 3.5f, 2.0f / 223.0f, -1.0f);
    float cby = fmaf((float)oy + 3.5f, 2.0f / 223.0f, -1.0f);
    float cbz = fmaf((float)oz + 3.5f, 2.0f / 223.0f, -1.0f);
    F3 qc;
    qc.x = fmaf(fmaf(M.m[0], cbx, fmaf(M.m[1], cby, M.m[2] * cbz)), 111.5f, 111.5f);
    qc.y = fmaf(fmaf(M.m[3], cbx, fmaf(M.m[4], cby, M.m[5] * cbz)), 111.5f, 111.5f);
    qc.z = fmaf(fmaf(M.m[6], cbx, fmaf(M.m[7], cby, M.m[8] * cbz)), 111.5f, 111.5f);
    return qc;
}

__device__ __forceinline__ bool tile_accept(F3 qc, F3 H) {
    return !(qc.x + H.x < BLO || qc.x - H.x > BHI ||
             qc.y + H.y < BLO || qc.y - H.y > BHI ||
             qc.z + H.z < BLO || qc.z - H.z > BHI);
}

__device__ __forceinline__ void qmap(const Mat3& M, int x, int y, int z,
                                     float& qx, float& qy, float& qz) {
    float bx = fmaf((float)x, 2.0f / 223.0f, -1.0f);
    float by = fmaf((float)y, 2.0f / 223.0f, -1.0f);
    float bz = fmaf((float)z, 2.0f / 223.0f, -1.0f);
    qx = fmaf(fmaf(M.m[0], bx, fmaf(M.m[1], by, M.m[2] * bz)), 111.5f, 111.5f);
    qy = fmaf(fmaf(M.m[3], bx, fmaf(M.m[4], by, M.m[5] * bz)), 111.5f, 111.5f);
    qz = fmaf(fmaf(M.m[6], bx, fmaf(M.m[7], by, M.m[8] * bz)), 111.5f, 111.5f);
}

__device__ __forceinline__ float fetch_d(const float* __restrict__ d, int z, int y, int x) {
    unsigned zz = (unsigned)(z - PAD), yy = (unsigned)(y - PAD), xx = (unsigned)(x - PAD);
    return (zz < (unsigned)SS && yy < (unsigned)SS && xx < (unsigned)SS)
        ? d[((int)zz * SS + (int)yy) * SS + (int)xx] : 0.0f;
}

__device__ __forceinline__ float fetch_T(const float* __restrict__ T, int z, int y, int x) {
    unsigned zz = (unsigned)z, yy = (unsigned)y, xx = (unsigned)x;
    return (zz < (unsigned)LL && yy < (unsigned)LL && xx < (unsigned)LL)
        ? T[((int)zz * LL + (int)yy) * LL + (int)xx] : 0.0f;
}

__device__ __forceinline__ float tri_T(const float* __restrict__ T, float qz, float qy, float qx) {
    int x0 = (int)floorf(qx), y0 = (int)floorf(qy), z0 = (int)floorf(qz);
    float wx = qx - (float)x0, wy = qy - (float)y0, wz = qz - (float)z0;
    float c000 = fetch_T(T, z0, y0, x0),     c001 = fetch_T(T, z0, y0, x0 + 1);
    float c010 = fetch_T(T, z0, y0 + 1, x0), c011 = fetch_T(T, z0, y0 + 1, x0 + 1);
    float c100 = fetch_T(T, z0 + 1, y0, x0),     c101 = fetch_T(T, z0 + 1, y0, x0 + 1);
    float c110 = fetch_T(T, z0 + 1, y0 + 1, x0), c111 = fetch_T(T, z0 + 1, y0 + 1, x0 + 1);
    float a00 = c000 + wx * (c001 - c000), a01 = c010 + wx * (c011 - c010);
    float a10 = c100 + wx * (c101 - c100), a11 = c110 + wx * (c111 - c110);
    float b0 = a00 + wy * (a01 - a00), b1 = a10 + wy * (a11 - a10);
    return b0 + wz * (b1 - b0);
}

__device__ __forceinline__ float tri_d_g(const float* __restrict__ d, float qz, float qy, float qx) {
    int x0 = (int)floorf(qx), y0 = (int)floorf(qy), z0 = (int)floorf(qz);
    float wx = qx - (float)x0, wy = qy - (float)y0, wz = qz - (float)z0;
    float c000 = fetch_d(d, z0, y0, x0),     c001 = fetch_d(d, z0, y0, x0 + 1);
    float c010 = fetch_d(d, z0, y0 + 1, x0), c011 = fetch_d(d, z0, y0 + 1, x0 + 1);
    float c100 = fetch_d(d, z0 + 1, y0, x0),     c101 = fetch_d(d, z0 + 1, y0, x0 + 1);
    float c110 = fetch_d(d, z0 + 1, y0 + 1, x0), c111 = fetch_d(d, z0 + 1, y0 + 1, x0 + 1);
    float a00 = c000 + wx * (c001 - c000), a01 = c010 + wx * (c011 - c010);
    float a10 = c100 + wx * (c101 - c100), a11 = c110 + wx * (c111 - c110);
    float b0 = a00 + wy * (a01 - a00), b1 = a10 + wy * (a11 - a10);
    return b0 + wz * (b1 - b0);
}

// trilinear from the pow2 LDS box
__device__ __forceinline__ float tri_lds(const float* __restrict__ S,
                                         float qx, float qy, float qz,
                                         int lox, int loy, int loz) {
    int x0 = (int)floorf(qx), y0 = (int)floorf(qy), z0 = (int)floorf(qz);
    float wx = qx - (float)x0, wy = qy - (float)y0, wz = qz - (float)z0;
    int i = ((z0 - loz) * GD + (y0 - loy)) * GD + (x0 - lox);
    float c000 = S[i],           c001 = S[i + 1];
    float c010 = S[i + GD],      c011 = S[i + GD + 1];
    float c100 = S[i + GD2],     c101 = S[i + GD2 + 1];
    float c110 = S[i + GD2 + GD], c111 = S[i + GD2 + GD + 1];
    float a00 = c000 + wx * (c001 - c000), a01 = c010 + wx * (c011 - c010);
    float a10 = c100 + wx * (c101 - c100), a11 = c110 + wx * (c111 - c110);
    float b0 = a00 + wy * (a01 - a00), b1 = a10 + wy * (a11 - a10);
    return b0 + wz * (b1 - b0);
}

// K1: rotated density for accepted tiles (writes every voxel of the tile) and
// fused per-tile column sums into Ssum.
__global__ __launch_bounds__(512) void k_rot_density(const float* __restrict__ d,
        float* __restrict__ T, float* __restrict__ Ssum, Mat3 M, F3 H) {
    int b = blockIdx.x;
    int ttx = b % NT1; int rr = b / NT1; int tty = rr % NT1; int ttz = rr / NT1;
    int ox = ttx * 8, oy = tty * 8, oz = ttz * 8;
    F3 qc = tile_center(M, ox, oy, oz);
    if (!tile_accept(qc, H)) return;

    int lox = (int)floorf(qc.x - H.x);
    int loy = (int)floorf(qc.y - H.y);
    int loz = (int)floorf(qc.z - H.z);

    __shared__ float S[GD3];
    __shared__ float Sc[512];
    int tid = threadIdx.x;
    int ix = tid & 15, iy = (tid >> 4) & 15, iz0 = tid >> 8;

    bool interior = (lox >= PAD) & (lox <= PAD + SS - GD) &
                    (loy >= PAD) & (loy <= PAD + SS - GD) &
                    (loz >= PAD) & (loz <= PAD + SS - GD);
    if (interior) {
        int off = ((loz + iz0 - PAD) * SS + (loy + iy - PAD)) * SS + (lox + ix - PAD);
        #pragma unroll
        for (int k = 0; k < 8; ++k)
            S[tid + k * 512] = d[off + k * 2 * SS2];
    } else {
        #pragma unroll
        for (int k = 0; k < 8; ++k)
            S[tid + k * 512] = fetch_d(d, loz + iz0 + 2 * k, loy + iy, lox + ix);
    }
    __syncthreads();

    int lx = tid & 7, ly = (tid >> 3) & 7, lz = tid >> 6;
    float fx = (float)lx - 3.5f, fy = (float)ly - 3.5f, fz = (float)lz - 3.5f;
    float qx = qc.x + fmaf(M.m[0], fx, fmaf(M.m[1], fy, M.m[2] * fz));
    float qy = qc.y + fmaf(M.m[3], fx, fmaf(M.m[4], fy, M.m[5] * fz));
    float qz = qc.z + fmaf(M.m[6], fx, fmaf(M.m[7], fy, M.m[8] * fz));
    float v = tri_lds(S, qx, qy, qz, lox, loy, loz);

    T[((oz + lz) * LL + (oy + ly)) * LL + (ox + lx)] = v;
    Sc[tid] = v;
    __syncthreads();
    if (tid < 64) {
        float s = 0.0f;
        #pragma unroll
        for (int k = 0; k < 8; ++k) s += Sc[tid + 64 * k];
        Ssum[ttz * LL2 + (oy + (tid >> 3)) * LL + (ox + (tid & 7))] = s;
    }
}

// pass B: per column, exclusive suffix of tile sums (in place) + accept run
__global__ __launch_bounds__(256) void k_suffix(float* __restrict__ Ssum,
        unsigned* __restrict__ Trun, Mat3 M, F3 H) {
    int col = blockIdx.x * 256 + threadIdx.x;      // grid 196 -> col < LL2 exactly
    int x = col % LL, y = col / LL;
    int tox = x & ~7, toy = y & ~7;
    int t0 = -1, t1 = -1;
    for (int t = 0; t < NT1; ++t) {
        F3 qc = tile_center(M, tox, toy, t << 3);
        if (tile_accept(qc, H)) { if (t0 < 0) t0 = t; t1 = t; }
    }
    Trun[col] = (t0 < 0) ? 0xFFFFu : (unsigned)(t0 | (t1 << 8));
    if (t0 < 0) return;
    float vbuf[NT1];
    #pragma unroll
    for (int t = 0; t < NT1; ++t) {
        bool a = (t >= t0) & (t <= t1);
        vbuf[t] = a ? Ssum[t * LL2 + col] : 0.0f;
    }
    float run = 0.0f;
    #pragma unroll
    for (int t = NT1 - 1; t >= 0; --t) {
        if (t >= t0 && t <= t1) Ssum[t * LL2 + col] = run;
        run += vbuf[t];
    }
}

// pass C: per (column, tile): local 8-cell reverse cumsum + exp, seeded by Ssum
__global__ __launch_bounds__(256) void k_exp(float* __restrict__ T,
        const float* __restrict__ Ssum, const unsigned* __restrict__ Trun) {
    int b = blockIdx.x;                    // 28*196 blocks
    int tz = b / 196;
    int col = (b - tz * 196) * 256 + threadIdx.x;
    unsigned tr = Trun[col];
    int t0 = (int)(tr & 0xFFu), t1 = (int)((tr >> 8) & 0xFFu);
    if (tz < t0 || tz > t1) return;
    float run = Ssum[tz * LL2 + col];
    int zb = tz << 3;
    float v[8];
    #pragma unroll
    for (int j = 0; j < 8; ++j) v[j] = T[(zb + 7 - j) * LL2 + col];
    #pragma unroll
    for (int j = 0; j < 8; ++j) {
        run += v[j];
        T[(zb + 7 - j) * LL2 + col] = __expf(-CABS * run);
    }
}

// view-ray weights W = d * exp(-c * suffix(d)) via 2-pass segmented scan
__global__ __launch_bounds__(256) void k_w_seg(const float* __restrict__ d,
                                               float* __restrict__ Dseg) {
    int t = blockIdx.x * 256 + threadIdx.x;
    if (t >= NSEG * SS2) return;
    int seg = t / SS2, col = t - seg * SS2;
    int zs = seg * SEGZ, ze = min(SS, zs + SEGZ);
    float run = 0.0f;
    for (int z = zs; z < ze; ++z) run += d[z * SS2 + col];
    Dseg[t] = run;
}

__global__ __launch_bounds__(256) void k_w_write(const float* __restrict__ d,
                                                 const float* __restrict__ Dseg,
                                                 float* __restrict__ W) {
    int t = blockIdx.x * 256 + threadIdx.x;
    if (t >= NSEG * SS2) return;
    int seg = t / SS2, col = t - seg * SS2;
    int zs = seg * SEGZ, ze = min(SS, zs + SEGZ);
    float run = 0.0f;
    for (int s2 = seg + 1; s2 < NSEG; ++s2) run += Dseg[s2 * SS2 + col];
    for (int z = ze - 1; z >= zs; --z) {
        float dv = d[z * SS2 + col];
        run += dv;
        W[z * SS2 + col] = dv * __expf(-CABS * run);
    }
}

// back-rotate + multiply by W + LDS column reduce + one atomic per column
__global__ __launch_bounds__(512) void k_back_acc(const float* __restrict__ T,
        const float* __restrict__ W, float* __restrict__ A, Mat3 M, F3 H) {
    int b = blockIdx.x;
    int ttx = b % NT3; int rr = b / NT3; int tty = rr % NT3; int ttz = rr / NT3;
    int ox = ttx * 8, oy = tty * 8, oz = ttz * 8;
    F3 qc = tile_center(M, ox + PAD, oy + PAD, oz + PAD);
    int lox = (int)floorf(qc.x - H.x);
    int loy = (int)floorf(qc.y - H.y);
    int loz = (int)floorf(qc.z - H.z);

    __shared__ float S[GD3];
    __shared__ float Sc[512];
    int tid = threadIdx.x;
    int ix = tid & 15, iy = (tid >> 4) & 15, iz0 = tid >> 8;

    bool interior = (lox >= 0) & (lox <= LL - GD) &
                    (loy >= 0) & (loy <= LL - GD) &
                    (loz >= 0) & (loz <= LL - GD);
    if (interior) {
        int off = ((loz + iz0) * LL + (loy + iy)) * LL + (lox + ix);
        #pragma unroll
        for (int k = 0; k < 8; ++k)
            S[tid + k * 512] = T[off + k * 2 * LL2];
    } else {
        #pragma unroll
        for (int k = 0; k < 8; ++k)
            S[tid + k * 512] = fetch_T(T, loz + iz0 + 2 * k, loy + iy, lox + ix);
    }
    __syncthreads();

    int lx = tid & 7, ly = (tid >> 3) & 7, lz = tid >> 6;
    int x = ox + lx, y = oy + ly, z = oz + lz;
    float v = 0.0f;
    if (x < SS && y < SS && z < SS) {
        float fx = (float)lx - 3.5f, fy = (float)ly - 3.5f, fz = (float)lz - 3.5f;
        float qx = qc.x + fmaf(M.m[0], fx, fmaf(M.m[1], fy, M.m[2] * fz));
        float qy = qc.y + fmaf(M.m[3], fx, fmaf(M.m[4], fy, M.m[5] * fz));
        float qz = qc.z + fmaf(M.m[6], fx, fmaf(M.m[7], fy, M.m[8] * fz));
        float u = tri_lds(S, qx, qy, qz, lox, loy, loz);
        v = u * W[(z * SS + y) * SS + x];
    }
    Sc[tid] = v;
    __syncthreads();
    if (tid < 64) {
        float s = 0.0f;
        #pragma unroll
        for (int k = 0; k < 8; ++k) s += Sc[tid + 64 * k];
        int xx = ox + (tid & 7), yy = oy + (tid >> 3);
        if (xx < SS && yy < SS) atomicAdd(&A[yy * SS + xx], s);
    }
}

__global__ __launch_bounds__(256) void k_combine(const float* __restrict__ A0,
        const float* __restrict__ A1, float* __restrict__ out, F3 c0, F3 c1) {
    int i = blockIdx.x * 256 + threadIdx.x;
    if (i >= 3 * SS2) return;
    int ch = i / SS2, col = i - ch * SS2;
    float r0 = (ch == 0) ? c0.x : ((ch == 1) ? c0.y : c0.z);
    float r1 = (ch == 0) ? c1.x : ((ch == 1) ? c1.y : c1.z);
    float o = CABS * (A0[col] * r0 + A1[col] * r1);
    out[i] = fminf(fmaxf(o, 0.0f), 1.0f);
}

// ---- minimal-workspace fallback (round-1 style, correctness insurance) ----
__global__ __launch_bounds__(256) void k_rot_full(const float* __restrict__ d,
                                                  float* __restrict__ T, Mat3 R) {
    int i = blockIdx.x * 256 + threadIdx.x;
    if (i >= LL3) return;
    int x = i % LL; int r = i / LL; int y = r % LL; int z = r / LL;
    float qx, qy, qz; qmap(R, x, y, z, qx, qy, qz);
    T[i] = tri_d_g(d, qz, qy, qx);
}

__global__ __launch_bounds__(256) void k_scan_full(float* __restrict__ T) {
    int col = blockIdx.x * 256 + threadIdx.x;
    if (col >= LL2) return;
    float run = 0.0f;
    for (int z = LL - 1; z >= 0; --z) {
        int idx = z * LL2 + col;
        run += T[idx];
        T[idx] = __expf(-CABS * run);
    }
}

__global__ __launch_bounds__(64) void k_fused_back(const float* __restrict__ T,
        const float* __restrict__ d, float* __restrict__ LA, Mat3 RT,
        float cr, float cg, float cb, int first) {
    int col = blockIdx.x * 64 + threadIdx.x;
    if (col >= SS2) return;
    int y = col / SS, x = col % SS;
    float run = 0.0f, acc = 0.0f;
    for (int z = SS - 1; z >= 0; --z) {
        float qx, qy, qz; qmap(RT, x + PAD, y + PAD, z + PAD, qx, qy, qz);
        float u = tri_T(T, qz, qy, qx);
        float dv = d[z * SS2 + col];
        run += dv;
        acc = fmaf(dv * __expf(-CABS * run), u, acc);
    }
    if (first) {
        LA[0 * SS2 + col] = acc * cr;
        LA[1 * SS2 + col] = acc * cg;
        LA[2 * SS2 + col] = acc * cb;
    } else {
        LA[0 * SS2 + col] += acc * cr;
        LA[1 * SS2 + col] += acc * cg;
        LA[2 * SS2 + col] += acc * cb;
    }
}

__global__ __launch_bounds__(256) void k_clip(const float* __restrict__ LA,
                                              float* __restrict__ out) {
    int i = blockIdx.x * 256 + threadIdx.x;
    if (i < 3 * SS2) out[i] = fminf(fmaxf(CABS * LA[i], 0.0f), 1.0f);
}

// host: R (ypr) and its transpose (== rot_matrix(-y,-p,'rpy')) as in reference
static void light_mats(const double ld_in[3], Mat3& R, Mat3& RT) {
    double n = sqrt(ld_in[0]*ld_in[0] + ld_in[1]*ld_in[1] + ld_in[2]*ld_in[2]);
    double l0 = ld_in[0]/n, l1 = ld_in[1]/n, l2 = ld_in[2]/n;
    double yv = -asin(l0);
    if (l2 < 0) yv = -M_PI - yv;
    double yd = yv * 180.0 / M_PI, pd = asin(l1) * 180.0 / M_PI;
    double yr = yd * M_PI / 180.0, pr = pd * M_PI / 180.0;
    float cy = (float)cos(yr), sy = (float)sin(yr), cp = (float)cos(pr), sp = (float)sin(pr);
    float m[9] = { cy,  sy*sp,  sy*cp,
                   0.f, cp,    -sp,
                  -sy,  cy*sp,  cy*cp };
    for (int i = 0; i < 9; ++i) R.m[i] = m[i];
    RT.m[0] = m[0]; RT.m[1] = m[3]; RT.m[2] = m[6];
    RT.m[3] = m[1]; RT.m[4] = m[4]; RT.m[5] = m[7];
    RT.m[6] = m[2]; RT.m[7] = m[5]; RT.m[8] = m[8];
}

static F3 half_span(const Mat3& M) {
    F3 h;
    h.x = 3.5f * (fabsf(M.m[0]) + fabsf(M.m[1]) + fabsf(M.m[2])) + 0.05f;
    h.y = 3.5f * (fabsf(M.m[3]) + fabsf(M.m[4]) + fabsf(M.m[5])) + 0.05f;
    h.z = 3.5f * (fabsf(M.m[6]) + fabsf(M.m[7]) + fabsf(M.m[8])) + 0.05f;
    return h;
}

extern "C" void kernel_launch(void* const* d_in, const int* in_sizes, int n_in,
                              void* d_out, int out_size, void* d_ws, size_t ws_size,
                              hipStream_t stream) {
    const float* d = (const float*)d_in[0];
    float* out = (float*)d_out;

    const double dirs[2][3] = { {2.0, 1.0, 1.0}, {-1.0, 0.5, 0.0} };
    F3 c0 = { 1.0f, 69.0f / 255.0f, 25.0f / 255.0f };
    F3 c1 = { 227.0f / 255.0f, 1.0f, 66.0f / 255.0f };
    Mat3 R[2], RT[2];
    light_mats(dirs[0], R[0], RT[0]);
    light_mats(dirs[1], R[1], RT[1]);
    F3 HF[2] = { half_span(R[0]),  half_span(R[1])  };
    F3 HB[2] = { half_span(RT[0]), half_span(RT[1]) };

    const size_t need_A = (size_t)(LL3 + NTZ * LL2 + SS3 + NSEG * SS2 + 2 * SS2 + LL2) * 4;

    if (ws_size >= need_A) {
        float* T    = (float*)d_ws;
        float* Ssum = T + LL3;
        float* W    = Ssum + NTZ * LL2;
        float* Dseg = W + SS3;
        float* A0   = Dseg + NSEG * SS2;
        float* A1   = A0 + SS2;
        unsigned* Trun = (unsigned*)(A1 + SS2);

        hipMemsetAsync(A0, 0, 2 * SS2 * sizeof(float), stream);
        k_w_seg  <<<(NSEG * SS2 + 255) / 256, 256, 0, stream>>>(d, Dseg);
        k_w_write<<<(NSEG * SS2 + 255) / 256, 256, 0, stream>>>(d, Dseg, W);
        for (int l = 0; l < 2; ++l) {
            k_rot_density<<<TPL1, 512, 0, stream>>>(d, T, Ssum, R[l], HF[l]);
            k_suffix     <<<196, 256, 0, stream>>>(Ssum, Trun, R[l], HF[l]);
            k_exp        <<<28 * 196, 256, 0, stream>>>(T, Ssum, Trun);
            k_back_acc   <<<TPL3, 512, 0, stream>>>(T, W, l ? A1 : A0, RT[l], HB[l]);
        }
        k_combine<<<(3 * SS2 + 255) / 256, 256, 0, stream>>>(A0, A1, out, c0, c1);
    } else {
        // minimal path: full-cube rotate + serial scan + fused back
        float* T  = (float*)d_ws;
        float* LA = T + LL3;
        for (int l = 0; l < 2; ++l) {
            k_rot_full <<<(LL3 + 255) / 256, 256, 0, stream>>>(d, T, R[l]);
            k_scan_full<<<(LL2 + 255) / 256, 256, 0, stream>>>(T);
            k_fused_back<<<(SS2 + 63) / 64, 64, 0, stream>>>(T, d, LA, RT[l],
                l ? c1.x : c0.x, l ? c1.y : c0.y, l ? c1.z : c0.z, l == 0);
        }
        k_clip<<<(3 * SS2 + 255) / 256, 256, 0, stream>>>(LA, out);
    }
}

// Round 7
// 193.676 us; speedup vs baseline: 1.2149x; 1.0469x over previous
//
#include <hip/hip_runtime.h>
#include <math.h>

#ifndef M_PI
#define M_PI 3.14159265358979323846
#endif

#define SS   129
#define LL   224
#define LL2  (LL*LL)
#define LL3  (LL*LL*LL)
#define SS2  (SS*SS)
#define SS3  (SS*SS*SS)
#define CABS 0.2f
#define PAD  48

#define BLO 45.5f
#define BHI 178.5f

#define NT1  28
#define TPL1 21952
#define NT3  17
#define TPL3 4913
#define NTZ  28
#define NSEG 4
#define SEGZ 33

#define GD   16
#define GD2  256
#define GD3  4096

struct Mat3 { float m[9]; };
struct F3   { float x, y, z; };

// q-coords of a tile center: SINGLE shared expression for every kernel that
// decides tile acceptance (bitwise-identical across kernels).
__device__ __forceinline__ F3 tile_center(const Mat3& M, int ox, int oy, int oz) {
    float cbx = fmaf((float)ox + 3.5f, 2.0f / 223.0f, -1.0f);
    float cby = fmaf((float)oy + 3.5f, 2.0f / 223.0f, -1.0f);
    float cbz = fmaf((float)oz + 3.5f, 2.0f / 223.0f, -1.0f);
    F3 qc;
    qc.x = fmaf(fmaf(M.m[0], cbx, fmaf(M.m[1], cby, M.m[2] * cbz)), 111.5f, 111.5f);
    qc.y = fmaf(fmaf(M.m[3], cbx, fmaf(M.m[4], cby, M.m[5] * cbz)), 111.5f, 111.5f);
    qc.z = fmaf(fmaf(M.m[6], cbx, fmaf(M.m[7], cby, M.m[8] * cbz)), 111.5f, 111.5f);
    return qc;
}

__device__ __forceinline__ bool tile_accept(F3 qc, F3 H) {
    return !(qc.x + H.x < BLO || qc.x - H.x > BHI ||
             qc.y + H.y < BLO || qc.y - H.y > BHI ||
             qc.z + H.z < BLO || qc.z - H.z > BHI);
}

__device__ __forceinline__ void qmap(const Mat3& M, int x, int y, int z,
                                     float& qx, float& qy, float& qz) {
    float bx = fmaf((float)x, 2.0f / 223.0f, -1.0f);
    float by = fmaf((float)y, 2.0f / 223.0f, -1.0f);
    float bz = fmaf((float)z, 2.0f / 223.0f, -1.0f);
    qx = fmaf(fmaf(M.m[0], bx, fmaf(M.m[1], by, M.m[2] * bz)), 111.5f, 111.5f);
    qy = fmaf(fmaf(M.m[3], bx, fmaf(M.m[4], by, M.m[5] * bz)), 111.5f, 111.5f);
    qz = fmaf(fmaf(M.m[6], bx, fmaf(M.m[7], by, M.m[8] * bz)), 111.5f, 111.5f);
}

__device__ __forceinline__ float fetch_d(const float* __restrict__ d, int z, int y, int x) {
    unsigned zz = (unsigned)(z - PAD), yy = (unsigned)(y - PAD), xx = (unsigned)(x - PAD);
    return (zz < (unsigned)SS && yy < (unsigned)SS && xx < (unsigned)SS)
        ? d[((int)zz * SS + (int)yy) * SS + (int)xx] : 0.0f;
}

__device__ __forceinline__ float fetch_T(const float* __restrict__ T, int z, int y, int x) {
    unsigned zz = (unsigned)z, yy = (unsigned)y, xx = (unsigned)x;
    return (zz < (unsigned)LL && yy < (unsigned)LL && xx < (unsigned)LL)
        ? T[((int)zz * LL + (int)yy) * LL + (int)xx] : 0.0f;
}

__device__ __forceinline__ float tri_T(const float* __restrict__ T, float qz, float qy, float qx) {
    int x0 = (int)floorf(qx), y0 = (int)floorf(qy), z0 = (int)floorf(qz);
    float wx = qx - (float)x0, wy = qy - (float)y0, wz = qz - (float)z0;
    float c000 = fetch_T(T, z0, y0, x0),     c001 = fetch_T(T, z0, y0, x0 + 1);
    float c010 = fetch_T(T, z0, y0 + 1, x0), c011 = fetch_T(T, z0, y0 + 1, x0 + 1);
    float c100 = fetch_T(T, z0 + 1, y0, x0),     c101 = fetch_T(T, z0 + 1, y0, x0 + 1);
    float c110 = fetch_T(T, z0 + 1, y0 + 1, x0), c111 = fetch_T(T, z0 + 1, y0 + 1, x0 + 1);
    float a00 = c000 + wx * (c001 - c000), a01 = c010 + wx * (c011 - c010);
    float a10 = c100 + wx * (c101 - c100), a11 = c110 + wx * (c111 - c110);
    float b0 = a00 + wy * (a01 - a00), b1 = a10 + wy * (a11 - a10);
    return b0 + wz * (b1 - b0);
}

__device__ __forceinline__ float tri_d_g(const float* __restrict__ d, float qz, float qy, float qx) {
    int x0 = (int)floorf(qx), y0 = (int)floorf(qy), z0 = (int)floorf(qz);
    float wx = qx - (float)x0, wy = qy - (float)y0, wz = qz - (float)z0;
    float c000 = fetch_d(d, z0, y0, x0),     c001 = fetch_d(d, z0, y0, x0 + 1);
    float c010 = fetch_d(d, z0, y0 + 1, x0), c011 = fetch_d(d, z0, y0 + 1, x0 + 1);
    float c100 = fetch_d(d, z0 + 1, y0, x0),     c101 = fetch_d(d, z0 + 1, y0, x0 + 1);
    float c110 = fetch_d(d, z0 + 1, y0 + 1, x0), c111 = fetch_d(d, z0 + 1, y0 + 1, x0 + 1);
    float a00 = c000 + wx * (c001 - c000), a01 = c010 + wx * (c011 - c010);
    float a10 = c100 + wx * (c101 - c100), a11 = c110 + wx * (c111 - c110);
    float b0 = a00 + wy * (a01 - a00), b1 = a10 + wy * (a11 - a10);
    return b0 + wz * (b1 - b0);
}

__device__ __forceinline__ float tri_lds(const float* __restrict__ S,
                                         float qx, float qy, float qz,
                                         int lox, int loy, int loz) {
    int x0 = (int)floorf(qx), y0 = (int)floorf(qy), z0 = (int)floorf(qz);
    float wx = qx - (float)x0, wy = qy - (float)y0, wz = qz - (float)z0;
    int i = ((z0 - loz) * GD + (y0 - loy)) * GD + (x0 - lox);
    float c000 = S[i],            c001 = S[i + 1];
    float c010 = S[i + GD],       c011 = S[i + GD + 1];
    float c100 = S[i + GD2],      c101 = S[i + GD2 + 1];
    float c110 = S[i + GD2 + GD], c111 = S[i + GD2 + GD + 1];
    float a00 = c000 + wx * (c001 - c000), a01 = c010 + wx * (c011 - c010);
    float a10 = c100 + wx * (c101 - c100), a11 = c110 + wx * (c111 - c110);
    float b0 = a00 + wy * (a01 - a00), b1 = a10 + wy * (a11 - a10);
    return b0 + wz * (b1 - b0);
}

// K1 (both lights): rotated density for accepted tiles. Writes:
//   T    = LOCAL in-tile inclusive suffix sum of density along z (per column)
//   Ssum = tile column totals
__global__ __launch_bounds__(512) void k_rot_density(const float* __restrict__ d,
        float* __restrict__ T0, float* __restrict__ T1,
        float* __restrict__ S0, float* __restrict__ S1,
        Mat3 M0, Mat3 M1, F3 H0, F3 H1, int lbase) {
    int b = blockIdx.x;
    int lofs = b / TPL1; b -= lofs * TPL1;
    int light = lbase + lofs;
    const Mat3 M = light ? M1 : M0;
    const F3  H  = light ? H1 : H0;
    float* __restrict__ T    = light ? T1 : T0;
    float* __restrict__ Ssum = light ? S1 : S0;

    int ttx = b % NT1; int rr = b / NT1; int tty = rr % NT1; int ttz = rr / NT1;
    int ox = ttx * 8, oy = tty * 8, oz = ttz * 8;
    F3 qc = tile_center(M, ox, oy, oz);
    if (!tile_accept(qc, H)) return;

    int lox = (int)floorf(qc.x - H.x);
    int loy = (int)floorf(qc.y - H.y);
    int loz = (int)floorf(qc.z - H.z);

    __shared__ float S[GD3];
    __shared__ float Sc[512];
    int tid = threadIdx.x;
    int ix = tid & 15, iy = (tid >> 4) & 15, iz0 = tid >> 8;

    bool interior = (lox >= PAD) & (lox <= PAD + SS - GD) &
                    (loy >= PAD) & (loy <= PAD + SS - GD) &
                    (loz >= PAD) & (loz <= PAD + SS - GD);
    if (interior) {
        int off = ((loz + iz0 - PAD) * SS + (loy + iy - PAD)) * SS + (lox + ix - PAD);
        #pragma unroll
        for (int k = 0; k < 8; ++k)
            S[tid + k * 512] = d[off + k * 2 * SS2];
    } else {
        #pragma unroll
        for (int k = 0; k < 8; ++k)
            S[tid + k * 512] = fetch_d(d, loz + iz0 + 2 * k, loy + iy, lox + ix);
    }
    __syncthreads();

    int lx = tid & 7, ly = (tid >> 3) & 7, lz = tid >> 6;
    float fx = (float)lx - 3.5f, fy = (float)ly - 3.5f, fz = (float)lz - 3.5f;
    float qx = qc.x + fmaf(M.m[0], fx, fmaf(M.m[1], fy, M.m[2] * fz));
    float qy = qc.y + fmaf(M.m[3], fx, fmaf(M.m[4], fy, M.m[5] * fz));
    float qz = qc.z + fmaf(M.m[6], fx, fmaf(M.m[7], fy, M.m[8] * fz));
    float v = tri_lds(S, qx, qy, qz, lox, loy, loz);

    Sc[tid] = v;
    __syncthreads();
    // inclusive local suffix along z (top-down accumulation, gated select)
    int colid = tid & 63;
    float s = 0.0f;
    #pragma unroll
    for (int k = 7; k >= 0; --k) {
        float t = Sc[colid + 64 * k];
        s += (k >= lz) ? t : 0.0f;
    }
    T[((oz + lz) * LL + (oy + ly)) * LL + (ox + lx)] = s;
    if (tid < 64)   // lz==0 -> s is the full tile column total
        Ssum[ttz * LL2 + (oy + (tid >> 3)) * LL + (ox + (tid & 7))] = s;
}

// pass B (both lights): per column, exclusive suffix-above of tile totals, in place
__global__ __launch_bounds__(256) void k_suffix(float* __restrict__ S0,
        float* __restrict__ S1, Mat3 M0, Mat3 M1, F3 H0, F3 H1, int lbase) {
    int b = blockIdx.x;
    int lofs = b / 196;
    int col = (b - lofs * 196) * 256 + threadIdx.x;   // < LL2 exactly
    int light = lbase + lofs;
    const Mat3 M = light ? M1 : M0;
    const F3  H  = light ? H1 : H0;
    float* __restrict__ Ssum = light ? S1 : S0;
    int x = col % LL, y = col / LL;
    int tox = x & ~7, toy = y & ~7;
    int t0 = -1, t1 = -1;
    for (int t = 0; t < NT1; ++t) {
        F3 qc = tile_center(M, tox, toy, t << 3);
        if (tile_accept(qc, H)) { if (t0 < 0) t0 = t; t1 = t; }
    }
    if (t0 < 0) return;
    float vbuf[NT1];
    #pragma unroll
    for (int t = 0; t < NT1; ++t) {
        bool a = (t >= t0) & (t <= t1);
        vbuf[t] = a ? Ssum[t * LL2 + col] : 0.0f;
    }
    float run = 0.0f;
    #pragma unroll
    for (int t = NT1 - 1; t >= 0; --t) {
        if (t >= t0 && t <= t1) Ssum[t * LL2 + col] = run;
        run += vbuf[t];
    }
}

// view-ray weights W = d * exp(-c * suffix(d)) via 2-pass segmented scan
__global__ __launch_bounds__(256) void k_w_seg(const float* __restrict__ d,
                                               float* __restrict__ Dseg) {
    int t = blockIdx.x * 256 + threadIdx.x;
    if (t >= NSEG * SS2) return;
    int seg = t / SS2, col = t - seg * SS2;
    int zs = seg * SEGZ, ze = min(SS, zs + SEGZ);
    float run = 0.0f;
    for (int z = zs; z < ze; ++z) run += d[z * SS2 + col];
    Dseg[t] = run;
}

__global__ __launch_bounds__(256) void k_w_write(const float* __restrict__ d,
                                                 const float* __restrict__ Dseg,
                                                 float* __restrict__ W) {
    int t = blockIdx.x * 256 + threadIdx.x;
    if (t >= NSEG * SS2) return;
    int seg = t / SS2, col = t - seg * SS2;
    int zs = seg * SEGZ, ze = min(SS, zs + SEGZ);
    float run = 0.0f;
    for (int s2 = seg + 1; s2 < NSEG; ++s2) run += Dseg[s2 * SS2 + col];
    for (int z = ze - 1; z >= zs; --z) {
        float dv = d[z * SS2 + col];
        run += dv;
        W[z * SS2 + col] = dv * __expf(-CABS * run);
    }
}

// K3 (both lights): stage exp(-c*(T_local + seed)) into LDS, back-rotate,
// multiply by W, LDS column reduce, one global atomic per column.
__global__ __launch_bounds__(512) void k_back_acc(const float* __restrict__ T0,
        const float* __restrict__ T1, const float* __restrict__ S0,
        const float* __restrict__ S1, const float* __restrict__ W,
        float* __restrict__ A0, float* __restrict__ A1,
        Mat3 M0, Mat3 M1, F3 H0, F3 H1, int lbase) {
    int b = blockIdx.x;
    int lofs = b / TPL3; b -= lofs * TPL3;
    int light = lbase + lofs;
    const Mat3 M = light ? M1 : M0;
    const F3  H  = light ? H1 : H0;
    const float* __restrict__ T    = light ? T1 : T0;
    const float* __restrict__ Ssum = light ? S1 : S0;
    float* __restrict__ A = light ? A1 : A0;

    int ttx = b % NT3; int rr = b / NT3; int tty = rr % NT3; int ttz = rr / NT3;
    int ox = ttx * 8, oy = tty * 8, oz = ttz * 8;
    F3 qc = tile_center(M, ox + PAD, oy + PAD, oz + PAD);
    int lox = (int)floorf(qc.x - H.x);
    int loy = (int)floorf(qc.y - H.y);
    int loz = (int)floorf(qc.z - H.z);

    __shared__ float S[GD3];
    __shared__ float Sc[512];
    int tid = threadIdx.x;
    int ix = tid & 15, iy = (tid >> 4) & 15, iz0 = tid >> 8;

    bool interior = (lox >= 0) & (lox <= LL - GD) &
                    (loy >= 0) & (loy <= LL - GD) &
                    (loz >= 0) & (loz <= LL - GD);
    if (interior) {
        int off  = ((loz + iz0) * LL + (loy + iy)) * LL + (lox + ix);
        int cofs = (loy + iy) * LL + (lox + ix);
        #pragma unroll
        for (int k = 0; k < 8; ++k) {
            int gz = loz + iz0 + 2 * k;
            float tv = T[off + k * 2 * LL2];
            float sd = Ssum[(gz >> 3) * LL2 + cofs];
            S[tid + k * 512] = __expf(-CABS * (tv + sd));
        }
    } else {
        #pragma unroll
        for (int k = 0; k < 8; ++k) {
            int gz = loz + iz0 + 2 * k, gy = loy + iy, gx = lox + ix;
            bool inb = ((unsigned)gz < (unsigned)LL) & ((unsigned)gy < (unsigned)LL)
                     & ((unsigned)gx < (unsigned)LL);
            float e = 0.0f;   // reference zero-pads the gather outside the volume
            if (inb) {
                float tv = T[(gz * LL + gy) * LL + gx];
                float sd = Ssum[(gz >> 3) * LL2 + gy * LL + gx];
                e = __expf(-CABS * (tv + sd));
            }
            S[tid + k * 512] = e;
        }
    }
    __syncthreads();

    int lx = tid & 7, ly = (tid >> 3) & 7, lz = tid >> 6;
    int x = ox + lx, y = oy + ly, z = oz + lz;
    float v = 0.0f;
    if (x < SS && y < SS && z < SS) {
        float fx = (float)lx - 3.5f, fy = (float)ly - 3.5f, fz = (float)lz - 3.5f;
        float qx = qc.x + fmaf(M.m[0], fx, fmaf(M.m[1], fy, M.m[2] * fz));
        float qy = qc.y + fmaf(M.m[3], fx, fmaf(M.m[4], fy, M.m[5] * fz));
        float qz = qc.z + fmaf(M.m[6], fx, fmaf(M.m[7], fy, M.m[8] * fz));
        float u = tri_lds(S, qx, qy, qz, lox, loy, loz);
        v = u * W[(z * SS + y) * SS + x];
    }
    Sc[tid] = v;
    __syncthreads();
    if (tid < 64) {
        float s = 0.0f;
        #pragma unroll
        for (int k = 0; k < 8; ++k) s += Sc[tid + 64 * k];
        int xx = ox + (tid & 7), yy = oy + (tid >> 3);
        if (xx < SS && yy < SS) atomicAdd(&A[yy * SS + xx], s);
    }
}

__global__ __launch_bounds__(256) void k_combine(const float* __restrict__ A0,
        const float* __restrict__ A1, float* __restrict__ out, F3 c0, F3 c1) {
    int i = blockIdx.x * 256 + threadIdx.x;
    if (i >= 3 * SS2) return;
    int ch = i / SS2, col = i - ch * SS2;
    float r0 = (ch == 0) ? c0.x : ((ch == 1) ? c0.y : c0.z);
    float r1 = (ch == 0) ? c1.x : ((ch == 1) ? c1.y : c1.z);
    float o = CABS * (A0[col] * r0 + A1[col] * r1);
    out[i] = fminf(fmaxf(o, 0.0f), 1.0f);
}

// ---- minimal-workspace fallback ----
__global__ __launch_bounds__(256) void k_rot_full(const float* __restrict__ d,
                                                  float* __restrict__ T, Mat3 R) {
    int i = blockIdx.x * 256 + threadIdx.x;
    if (i >= LL3) return;
    int x = i % LL; int r = i / LL; int y = r % LL; int z = r / LL;
    float qx, qy, qz; qmap(R, x, y, z, qx, qy, qz);
    T[i] = tri_d_g(d, qz, qy, qx);
}

__global__ __launch_bounds__(256) void k_scan_full(float* __restrict__ T) {
    int col = blockIdx.x * 256 + threadIdx.x;
    if (col >= LL2) return;
    float run = 0.0f;
    for (int z = LL - 1; z >= 0; --z) {
        int idx = z * LL2 + col;
        run += T[idx];
        T[idx] = __expf(-CABS * run);
    }
}

__global__ __launch_bounds__(64) void k_fused_back(const float* __restrict__ T,
        const float* __restrict__ d, float* __restrict__ LA, Mat3 RT,
        float cr, float cg, float cb, int first) {
    int col = blockIdx.x * 64 + threadIdx.x;
    if (col >= SS2) return;
    int y = col / SS, x = col % SS;
    float run = 0.0f, acc = 0.0f;
    for (int z = SS - 1; z >= 0; --z) {
        float qx, qy, qz; qmap(RT, x + PAD, y + PAD, z + PAD, qx, qy, qz);
        float u = tri_T(T, qz, qy, qx);
        float dv = d[z * SS2 + col];
        run += dv;
        acc = fmaf(dv * __expf(-CABS * run), u, acc);
    }
    if (first) {
        LA[0 * SS2 + col] = acc * cr;
        LA[1 * SS2 + col] = acc * cg;
        LA[2 * SS2 + col] = acc * cb;
    } else {
        LA[0 * SS2 + col] += acc * cr;
        LA[1 * SS2 + col] += acc * cg;
        LA[2 * SS2 + col] += acc * cb;
    }
}

__global__ __launch_bounds__(256) void k_clip(const float* __restrict__ LA,
                                              float* __restrict__ out) {
    int i = blockIdx.x * 256 + threadIdx.x;
    if (i < 3 * SS2) out[i] = fminf(fmaxf(CABS * LA[i], 0.0f), 1.0f);
}

static void light_mats(const double ld_in[3], Mat3& R, Mat3& RT) {
    double n = sqrt(ld_in[0]*ld_in[0] + ld_in[1]*ld_in[1] + ld_in[2]*ld_in[2]);
    double l0 = ld_in[0]/n, l1 = ld_in[1]/n, l2 = ld_in[2]/n;
    double yv = -asin(l0);
    if (l2 < 0) yv = -M_PI - yv;
    double yd = yv * 180.0 / M_PI, pd = asin(l1) * 180.0 / M_PI;
    double yr = yd * M_PI / 180.0, pr = pd * M_PI / 180.0;
    float cy = (float)cos(yr), sy = (float)sin(yr), cp = (float)cos(pr), sp = (float)sin(pr);
    float m[9] = { cy,  sy*sp,  sy*cp,
                   0.f, cp,    -sp,
                  -sy,  cy*sp,  cy*cp };
    for (int i = 0; i < 9; ++i) R.m[i] = m[i];
    RT.m[0] = m[0]; RT.m[1] = m[3]; RT.m[2] = m[6];
    RT.m[3] = m[1]; RT.m[4] = m[4]; RT.m[5] = m[7];
    RT.m[6] = m[2]; RT.m[7] = m[5]; RT.m[8] = m[8];
}

static F3 half_span(const Mat3& M) {
    F3 h;
    h.x = 3.5f * (fabsf(M.m[0]) + fabsf(M.m[1]) + fabsf(M.m[2])) + 0.05f;
    h.y = 3.5f * (fabsf(M.m[3]) + fabsf(M.m[4]) + fabsf(M.m[5])) + 0.05f;
    h.z = 3.5f * (fabsf(M.m[6]) + fabsf(M.m[7]) + fabsf(M.m[8])) + 0.05f;
    return h;
}

extern "C" void kernel_launch(void* const* d_in, const int* in_sizes, int n_in,
                              void* d_out, int out_size, void* d_ws, size_t ws_size,
                              hipStream_t stream) {
    const float* d = (const float*)d_in[0];
    float* out = (float*)d_out;

    const double dirs[2][3] = { {2.0, 1.0, 1.0}, {-1.0, 0.5, 0.0} };
    F3 c0 = { 1.0f, 69.0f / 255.0f, 25.0f / 255.0f };
    F3 c1 = { 227.0f / 255.0f, 1.0f, 66.0f / 255.0f };
    Mat3 R[2], RT[2];
    light_mats(dirs[0], R[0], RT[0]);
    light_mats(dirs[1], R[1], RT[1]);
    F3 HF[2] = { half_span(R[0]),  half_span(R[1])  };
    F3 HB[2] = { half_span(RT[0]), half_span(RT[1]) };

    const size_t per_light = (size_t)(LL3 + NTZ * LL2);
    const size_t common    = (size_t)(SS3 + NSEG * SS2 + 2 * SS2);
    const size_t need_A = (2 * per_light + common) * 4;   // ~111 MB
    const size_t need_B = (per_light + common) * 4;       // ~60 MB

    if (ws_size >= need_A) {
        float* T0 = (float*)d_ws;
        float* S0 = T0 + LL3;
        float* T1 = S0 + NTZ * LL2;
        float* S1 = T1 + LL3;
        float* W    = S1 + NTZ * LL2;
        float* Dseg = W + SS3;
        float* A0   = Dseg + NSEG * SS2;
        float* A1   = A0 + SS2;
        hipMemsetAsync(A0, 0, 2 * SS2 * sizeof(float), stream);
        k_w_seg  <<<(NSEG * SS2 + 255) / 256, 256, 0, stream>>>(d, Dseg);
        k_w_write<<<(NSEG * SS2 + 255) / 256, 256, 0, stream>>>(d, Dseg, W);
        k_rot_density<<<2 * TPL1, 512, 0, stream>>>(d, T0, T1, S0, S1,
                                                    R[0], R[1], HF[0], HF[1], 0);
        k_suffix     <<<2 * 196, 256, 0, stream>>>(S0, S1, R[0], R[1], HF[0], HF[1], 0);
        k_back_acc   <<<2 * TPL3, 512, 0, stream>>>(T0, T1, S0, S1, W, A0, A1,
                                                    RT[0], RT[1], HB[0], HB[1], 0);
        k_combine<<<(3 * SS2 + 255) / 256, 256, 0, stream>>>(A0, A1, out, c0, c1);
    } else if (ws_size >= need_B) {
        float* T0 = (float*)d_ws;
        float* S0 = T0 + LL3;
        float* W    = S0 + NTZ * LL2;
        float* Dseg = W + SS3;
        float* A0   = Dseg + NSEG * SS2;
        float* A1   = A0 + SS2;
        hipMemsetAsync(A0, 0, 2 * SS2 * sizeof(float), stream);
        k_w_seg  <<<(NSEG * SS2 + 255) / 256, 256, 0, stream>>>(d, Dseg);
        k_w_write<<<(NSEG * SS2 + 255) / 256, 256, 0, stream>>>(d, Dseg, W);
        for (int l = 0; l < 2; ++l) {
            k_rot_density<<<TPL1, 512, 0, stream>>>(d, T0, T0, S0, S0,
                                                    R[0], R[1], HF[0], HF[1], l);
            k_suffix     <<<196, 256, 0, stream>>>(S0, S0, R[0], R[1], HF[0], HF[1], l);
            k_back_acc   <<<TPL3, 512, 0, stream>>>(T0, T0, S0, S0, W, A0, A1,
                                                    RT[0], RT[1], HB[0], HB[1], l);
        }
        k_combine<<<(3 * SS2 + 255) / 256, 256, 0, stream>>>(A0, A1, out, c0, c1);
    } else {
        float* T  = (float*)d_ws;
        float* LA = T + LL3;
        for (int l = 0; l < 2; ++l) {
            k_rot_full <<<(LL3 + 255) / 256, 256, 0, stream>>>(d, T, R[l]);
            k_scan_full<<<(LL2 + 255) / 256, 256, 0, stream>>>(T);
            k_fused_back<<<(SS2 + 63) / 64, 64, 0, stream>>>(T, d, LA, RT[l],
                l ? c1.x : c0.x, l ? c1.y : c0.y, l ? c1.z : c0.z, l == 0);
        }
        k_clip<<<(3 * SS2 + 255) / 256, 256, 0, stream>>>(LA, out);
    }
}